// Round 5
// baseline (174.816 us; speedup 1.0000x reference)
//
#include <hip/hip_runtime.h>
#include <hip/hip_bf16.h>

#define HW 4096
#define CC 64
#define NB 4

typedef short bf16x8 __attribute__((ext_vector_type(8)));
typedef float f32x4 __attribute__((ext_vector_type(4)));

// workspace layout (byte offsets)
#define OFF_F  0                      // bf16 [b][n][8]     262144 B
#define OFF_G  262144                 // bf16 [b][n][8]     262144 B
#define OFF_H  524288                 // bf16 [b][c][n]    2097152 B
#define OFF_ZI 2621440                // f32  [b][n]         65536 B
#define OFF_O  2686976                // bf16 [4hx][b][c][m] 8388608 B
// total ~10.56 MB

__device__ __forceinline__ float bf2f(short s) {
    unsigned u = ((unsigned)(unsigned short)s) << 16;
    return __uint_as_float(u);
}

// ---------------------------------------------------------------------------
// Kernel 1: f/g/h 1x1 convs. Thread = one pixel, all 80 output rows.
// Grid MUST be (HW/256, NB) = (16, 4): one thread per pixel.
// Weight rows are thread-uniform -> scalar loads; x[64] held in VGPRs.
// f,g: bf16 [b][n][8]; h: bf16 [b][c][n] (transposed for k_attn B-fragments).
// ---------------------------------------------------------------------------
__global__ __launch_bounds__(256) void k_prep(
    const float* __restrict__ x,
    const float* __restrict__ Wf, const float* __restrict__ bf,
    const float* __restrict__ Wg, const float* __restrict__ bg,
    const float* __restrict__ Wh, const float* __restrict__ bh,
    __hip_bfloat16* __restrict__ fb, __hip_bfloat16* __restrict__ gb,
    __hip_bfloat16* __restrict__ hb)
{
    const int b = blockIdx.y;
    const int n = blockIdx.x * 256 + (int)threadIdx.x;   // 0..4095

    float xv[64];
    const float* xb = x + (size_t)b * (CC * HW) + n;
#pragma unroll
    for (int c = 0; c < 64; ++c) xv[c] = xb[(size_t)c * HW];

    const size_t bn = (size_t)b * HW + n;

    // f and g rows (8 each)
    __hip_bfloat16 fr[8], gr[8];
#pragma unroll
    for (int r = 0; r < 8; ++r) {
        float accf = bf[r], accg = bg[r];
        const float* wfr = Wf + r * 64;
        const float* wgr = Wg + r * 64;
#pragma unroll
        for (int c = 0; c < 64; c += 4) {
            const float4 wf4 = *(const float4*)(wfr + c);
            const float4 wg4 = *(const float4*)(wgr + c);
            accf += wf4.x * xv[c] + wf4.y * xv[c + 1] + wf4.z * xv[c + 2] + wf4.w * xv[c + 3];
            accg += wg4.x * xv[c] + wg4.y * xv[c + 1] + wg4.z * xv[c + 2] + wg4.w * xv[c + 3];
        }
        fr[r] = __float2bfloat16(accf);
        gr[r] = __float2bfloat16(accg);
    }
    *(float4*)(fb + bn * 8) = *(const float4*)fr;
    *(float4*)(gb + bn * 8) = *(const float4*)gr;

    // h rows (64), stored transposed [b][c][n]
#pragma unroll 2
    for (int r = 0; r < 64; ++r) {
        float acc = bh[r];
        const float* whr = Wh + r * 64;
#pragma unroll
        for (int c = 0; c < 64; c += 4) {
            const float4 w4 = *(const float4*)(whr + c);
            acc += w4.x * xv[c] + w4.y * xv[c + 1] + w4.z * xv[c + 2] + w4.w * xv[c + 3];
        }
        hb[((size_t)(b * 64 + r)) * HW + n] = __float2bfloat16(acc);
    }
}

// ---------------------------------------------------------------------------
// Kernel 2: zinv[b][n] = 1 / sum_i exp(f_i . g_n). Block owns 64 n and ALL i.
// All of f (64 KB) staged in LDS once; wave w covers i-strips w*16 + it*64.
// ---------------------------------------------------------------------------
__global__ __launch_bounds__(256) void k_z(
    const __hip_bfloat16* __restrict__ fb, const __hip_bfloat16* __restrict__ gb,
    float* __restrict__ zinv)
{
    __shared__ __align__(16) __hip_bfloat16 fS[4096 * 8];   // 64 KB
    __shared__ __align__(16) __hip_bfloat16 gS[64 * 8];
    __shared__ float zred[4][64];

    const int nt = blockIdx.x, b = blockIdx.y;
    const int n0 = nt * 64;
    const int tid = (int)threadIdx.x;
    const int w = tid >> 6, lane = tid & 63, quad = lane >> 4, l15 = lane & 15;

    const float4* fsrc = (const float4*)(fb + (size_t)b * HW * 8);
#pragma unroll
    for (int q = 0; q < 16; ++q)
        ((float4*)fS)[q * 256 + tid] = fsrc[q * 256 + tid];
    if (tid < 64)
        *(float4*)&gS[tid * 8] = *(const float4*)(gb + ((size_t)b * HW + n0 + tid) * 8);
    __syncthreads();

    const f32x4 cz = {0.f, 0.f, 0.f, 0.f};
    bf16x8 bgf[4];
#pragma unroll
    for (int ns = 0; ns < 4; ++ns) {
        bf16x8 v = {0, 0, 0, 0, 0, 0, 0, 0};
        if (quad == 0) v = *(const bf16x8*)&gS[(ns * 16 + l15) * 8];
        bgf[ns] = v;
    }

    float z[4] = {0.f, 0.f, 0.f, 0.f};
    for (int it = 0; it < 64; ++it) {
        const int i = it * 64 + w * 16;
        bf16x8 afr = {0, 0, 0, 0, 0, 0, 0, 0};
        if (quad == 0) afr = *(const bf16x8*)&fS[(i + l15) * 8];
#pragma unroll
        for (int ns = 0; ns < 4; ++ns) {
            f32x4 s = __builtin_amdgcn_mfma_f32_16x16x32_bf16(afr, bgf[ns], cz, 0, 0, 0);
            z[ns] += __expf(s[0]) + __expf(s[1]) + __expf(s[2]) + __expf(s[3]);
        }
    }

#pragma unroll
    for (int ns = 0; ns < 4; ++ns) {
        float v = z[ns];
        v += __shfl_xor(v, 16);
        v += __shfl_xor(v, 32);
        if (quad == 0) zred[w][ns * 16 + l15] = v;
    }
    __syncthreads();
    if (tid < 64) {
        float s = zred[0][tid] + zred[1][tid] + zred[2][tid] + zred[3][tid];
        zinv[(size_t)b * HW + n0 + tid] = 1.0f / s;
    }
}

// ---------------------------------------------------------------------------
// Kernel 3: attention. Per 64n-chunk: MFMA s-tile, p=exp(s)*zinv[n] (+tri
// mask), P->LDS bf16, MFMA P x H. Register-prefetch of next chunk's h/g/zinv
// overlaps VMEM with compute. NO atomics: each (hx,b,mt) block stores its
// own bf16 partial tile (coalesced), reduced in k_epi.
// ---------------------------------------------------------------------------
__global__ __launch_bounds__(256) void k_attn(
    const __hip_bfloat16* __restrict__ fb, const __hip_bfloat16* __restrict__ gb,
    const __hip_bfloat16* __restrict__ hb, const float* __restrict__ zinv,
    __hip_bfloat16* __restrict__ opart)
{
    __shared__ __align__(16) __hip_bfloat16 gS[64 * 8];
    __shared__ __align__(16) float zS[64];
    __shared__ __align__(16) __hip_bfloat16 hT[64 * 72];
    __shared__ __align__(16) __hip_bfloat16 pT[64 * 72];

    const int hx = blockIdx.x;               // 0..3 n-split
    const int b  = blockIdx.y;
    const int r  = blockIdx.z;
    const int mt = (r < 32) ? r : 95 - r;    // fold for load balance
    const int m0 = mt * 64;
    const int tid = (int)threadIdx.x;
    const int w = tid >> 6, lane = tid & 63, quad = lane >> 4, l15 = lane & 15;

    // hT staging coords for this thread (2 float4 = 32 B of the 8 KB tile)
    const int c0s = tid >> 3,          ch0 = tid & 7;
    const int c1s = (256 + tid) >> 3,  ch1 = (256 + tid) & 7;

    const f32x4 cz = {0.f, 0.f, 0.f, 0.f};

    bf16x8 af = {0, 0, 0, 0, 0, 0, 0, 0};
    if (quad == 0)
        af = *(const bf16x8*)(fb + ((size_t)b * HW + m0 + w * 16 + l15) * 8);

    f32x4 accO[4];
#pragma unroll
    for (int i = 0; i < 4; ++i) accO[i] = cz;

    const int nc0 = mt + hx;
    float4 hv0 = make_float4(0.f, 0.f, 0.f, 0.f);
    float4 hv1 = hv0, gv = hv0, zv = hv0;
    if (nc0 < 64) {   // prefetch first chunk
        const int n0 = nc0 * 64;
        hv0 = *(const float4*)(hb + ((size_t)(b * 64 + c0s)) * HW + n0 + ch0 * 8);
        hv1 = *(const float4*)(hb + ((size_t)(b * 64 + c1s)) * HW + n0 + ch1 * 8);
        if (tid < 64)      gv = *(const float4*)(gb + ((size_t)b * HW + n0 + tid) * 8);
        else if (tid < 80) zv = *(const float4*)(zinv + (size_t)b * HW + n0 + (tid - 64) * 4);
    }

    for (int nc = nc0; nc < 64; nc += 4) {
        __syncthreads();   // previous phase-B LDS reads complete
        *(float4*)&hT[c0s * 72 + ch0 * 8] = hv0;
        *(float4*)&hT[c1s * 72 + ch1 * 8] = hv1;
        if (tid < 64)      *(float4*)&gS[tid * 8] = gv;
        else if (tid < 80) *(float4*)&zS[(tid - 64) * 4] = zv;

        const int nn = nc + 4;
        if (nn < 64) {     // prefetch next chunk while computing this one
            const int n1 = nn * 64;
            hv0 = *(const float4*)(hb + ((size_t)(b * 64 + c0s)) * HW + n1 + ch0 * 8);
            hv1 = *(const float4*)(hb + ((size_t)(b * 64 + c1s)) * HW + n1 + ch1 * 8);
            if (tid < 64)      gv = *(const float4*)(gb + ((size_t)b * HW + n1 + tid) * 8);
            else if (tid < 80) zv = *(const float4*)(zinv + (size_t)b * HW + n1 + (tid - 64) * 4);
        }
        __syncthreads();

        const int n0 = nc * 64;
        const bool diag = (nc == mt);
        // ---- phase A: s = f.g^T; p = exp(s)*zinv; mask; -> pT (wave-private rows)
#pragma unroll
        for (int ns = 0; ns < 4; ++ns) {
            bf16x8 bg = {0, 0, 0, 0, 0, 0, 0, 0};
            if (quad == 0) bg = *(const bf16x8*)&gS[(ns * 16 + l15) * 8];
            f32x4 s = __builtin_amdgcn_mfma_f32_16x16x32_bf16(af, bg, cz, 0, 0, 0);
            const float zi = zS[ns * 16 + l15];
#pragma unroll
            for (int j = 0; j < 4; ++j) {
                float p = __expf(s[j]) * zi;
                if (diag) {
                    const int m = m0 + w * 16 + quad * 4 + j;
                    const int n = n0 + ns * 16 + l15;
                    if (n < m) p = 0.f;
                }
                pT[(w * 16 + quad * 4 + j) * 72 + ns * 16 + l15] = __float2bfloat16(p);
            }
        }
        // ---- phase B: accO += P x H ----
#pragma unroll
        for (int kb = 0; kb < 2; ++kb) {
            const bf16x8 ap =
                *(const bf16x8*)&pT[(w * 16 + l15) * 72 + kb * 32 + quad * 8];
#pragma unroll
            for (int cs = 0; cs < 4; ++cs) {
                const bf16x8 bh2 =
                    *(const bf16x8*)&hT[(cs * 16 + l15) * 72 + kb * 32 + quad * 8];
                accO[cs] = __builtin_amdgcn_mfma_f32_16x16x32_bf16(ap, bh2, accO[cs], 0, 0, 0);
            }
        }
    }

    // ---- epilogue: coalesced bf16 partial store, opart[hx][b][c][m] ----
#pragma unroll
    for (int cs = 0; cs < 4; ++cs) {
        const int c = cs * 16 + l15;
        __hip_bfloat16 tmp[4];
#pragma unroll
        for (int j = 0; j < 4; ++j) tmp[j] = __float2bfloat16(accO[cs][j]);
        *(float2*)(opart + ((size_t)((hx * NB + b) * 64 + c)) * HW + m0 + w * 16 + quad * 4) =
            *(const float2*)tmp;
    }
}

// ---------------------------------------------------------------------------
// Kernel 4: y = gamma * (sum of 4 partials) + x   (8 floats per thread)
// 1,048,576 output elements / 8 per thread = 131,072 threads = 512 blocks.
// ---------------------------------------------------------------------------
__global__ __launch_bounds__(256) void k_epi(
    const __hip_bfloat16* __restrict__ opart, const float* __restrict__ x,
    const float* __restrict__ gamma, float* __restrict__ y)
{
    const int t = blockIdx.x * 256 + (int)threadIdx.x;   // 131,072 threads
    const size_t e0 = (size_t)t * 8;
    const float ga = gamma[0];

    float acc[8] = {0, 0, 0, 0, 0, 0, 0, 0};
#pragma unroll
    for (int h = 0; h < 4; ++h) {
        const bf16x8 v = *(const bf16x8*)(opart + (size_t)h * (NB * CC * HW) + e0);
#pragma unroll
        for (int k = 0; k < 8; ++k) acc[k] += bf2f(v[k]);
    }
    const float4 x0 = *(const float4*)(x + e0);
    const float4 x1 = *(const float4*)(x + e0 + 4);
    float4 y0, y1;
    y0.x = ga * acc[0] + x0.x; y0.y = ga * acc[1] + x0.y;
    y0.z = ga * acc[2] + x0.z; y0.w = ga * acc[3] + x0.w;
    y1.x = ga * acc[4] + x1.x; y1.y = ga * acc[5] + x1.y;
    y1.z = ga * acc[6] + x1.z; y1.w = ga * acc[7] + x1.w;
    *(float4*)(y + e0) = y0;
    *(float4*)(y + e0 + 4) = y1;
}

extern "C" void kernel_launch(void* const* d_in, const int* in_sizes, int n_in,
                              void* d_out, int out_size, void* d_ws, size_t ws_size,
                              hipStream_t stream)
{
    const float* x     = (const float*)d_in[0];
    const float* Wf    = (const float*)d_in[1];
    const float* bf    = (const float*)d_in[2];
    const float* Wg    = (const float*)d_in[3];
    const float* bg    = (const float*)d_in[4];
    const float* Wh    = (const float*)d_in[5];
    const float* bh    = (const float*)d_in[6];
    const float* gamma = (const float*)d_in[7];

    char* ws = (char*)d_ws;
    __hip_bfloat16* fb = (__hip_bfloat16*)(ws + OFF_F);
    __hip_bfloat16* gb = (__hip_bfloat16*)(ws + OFF_G);
    __hip_bfloat16* hb = (__hip_bfloat16*)(ws + OFF_H);
    float* zinv = (float*)(ws + OFF_ZI);
    __hip_bfloat16* opart = (__hip_bfloat16*)(ws + OFF_O);
    float* y = (float*)d_out;

    k_prep<<<dim3(16, 4), 256, 0, stream>>>(x, Wf, bf, Wg, bg, Wh, bh, fb, gb, hb);
    k_z<<<dim3(64, 4), 256, 0, stream>>>(fb, gb, zinv);
    k_attn<<<dim3(4, 4, 64), 256, 0, stream>>>(fb, gb, hb, zinv, opart);
    k_epi<<<512, 256, 0, stream>>>(opart, x, gamma, y);
}

// Round 6
// 117.924 us; speedup vs baseline: 1.4825x; 1.4825x over previous
//
#include <hip/hip_runtime.h>
#include <hip/hip_bf16.h>

#define HW 4096
#define CC 64
#define NB 4

typedef short bf16x8 __attribute__((ext_vector_type(8)));
typedef float f32x4 __attribute__((ext_vector_type(4)));

// workspace layout (byte offsets)
#define OFF_F  0                      // bf16 [b][n][8]     262144 B
#define OFF_G  262144                 // bf16 [b][n][8]     262144 B
#define OFF_H  524288                 // bf16 [b][c][n]    2097152 B
#define OFF_ZI 2621440                // f32  [b][n]         65536 B
#define OFF_O  2686976                // bf16 [4hx][b][c][m] 8388608 B
// total ~10.56 MB

__device__ __forceinline__ float bf2f(short s) {
    unsigned u = ((unsigned)(unsigned short)s) << 16;
    return __uint_as_float(u);
}

// ---------------------------------------------------------------------------
// Kernel 1 (MFMA): Y[80,64] = W_all @ X[64,64npix] + bias, per 64-pixel tile.
// W A-fragments live in registers (one-time load; R5's 70us was scalar-L1
// thrash from re-reading 20KB of W per row). X staged transposed in LDS bf16.
// Rows 0-7 -> fb[b][n][8], 8-15 -> gb[b][n][8] (via LDS transpose),
// rows 16-79 -> hb[b][c][n] direct.
// ---------------------------------------------------------------------------
__global__ __launch_bounds__(256) void k_prep(
    const float* __restrict__ x,
    const float* __restrict__ Wf, const float* __restrict__ bf,
    const float* __restrict__ Wg, const float* __restrict__ bg,
    const float* __restrict__ Wh, const float* __restrict__ bh,
    __hip_bfloat16* __restrict__ fb, __hip_bfloat16* __restrict__ gb,
    __hip_bfloat16* __restrict__ hb)
{
    __shared__ __align__(16) __hip_bfloat16 xT[64 * 72];   // [n][c], stride 72
    __shared__ __align__(16) __hip_bfloat16 fgT[64 * 24];  // [n][16 rows], stride 24

    const int b  = blockIdx.y;
    const int n0 = blockIdx.x * 64;
    const int tid = (int)threadIdx.x;
    const int w = tid >> 6, lane = tid & 63, quad = lane >> 4, l15 = lane & 15;

    // ---- stage xT[n][c] (bf16): thread owns n=lane, c-pairs {w,w+4,...} ----
    {
        const int n = lane;
        const float* xb = x + (size_t)b * (CC * HW) + n0 + n;
#pragma unroll
        for (int i = 0; i < 8; ++i) {
            const int c = (w + 4 * i) * 2;
            const float v0 = xb[(size_t)c * HW];
            const float v1 = xb[(size_t)(c + 1) * HW];
            __hip_bfloat16 t[2] = {__float2bfloat16(v0), __float2bfloat16(v1)};
            *reinterpret_cast<unsigned*>(&xT[n * 72 + c]) =
                *reinterpret_cast<const unsigned*>(t);
        }
    }

    // ---- W A-fragments in registers: wa[mt][kk], row = mt*16 + l15 ----
    bf16x8 wa[5][2];
#pragma unroll
    for (int mt = 0; mt < 5; ++mt) {
        const int row = mt * 16 + l15;
        const float* src = (row < 8) ? (Wf + row * 64)
                         : (row < 16) ? (Wg + (row - 8) * 64)
                                      : (Wh + (row - 16) * 64);
#pragma unroll
        for (int kk = 0; kk < 2; ++kk) {
            const float4 a = *(const float4*)(src + kk * 32 + quad * 8);
            const float4 c4 = *(const float4*)(src + kk * 32 + quad * 8 + 4);
            __hip_bfloat16 t[8];
            t[0] = __float2bfloat16(a.x);  t[1] = __float2bfloat16(a.y);
            t[2] = __float2bfloat16(a.z);  t[3] = __float2bfloat16(a.w);
            t[4] = __float2bfloat16(c4.x); t[5] = __float2bfloat16(c4.y);
            t[6] = __float2bfloat16(c4.z); t[7] = __float2bfloat16(c4.w);
            wa[mt][kk] = *reinterpret_cast<const bf16x8*>(t);
        }
    }

    // ---- bias into accumulators: D row = quad*4 + r ----
    f32x4 acc[5];
#pragma unroll
    for (int mt = 0; mt < 5; ++mt) {
#pragma unroll
        for (int r = 0; r < 4; ++r) {
            const int grow = mt * 16 + quad * 4 + r;
            acc[mt][r] = (grow < 8) ? bf[grow]
                       : (grow < 16) ? bg[grow - 8]
                                     : bh[grow - 16];
        }
    }

    __syncthreads();

    // ---- B-fragments (wave w owns pixels n0 + w*16 + l15) and MFMA ----
    const bf16x8 b0 = *(const bf16x8*)&xT[(w * 16 + l15) * 72 + quad * 8];
    const bf16x8 b1 = *(const bf16x8*)&xT[(w * 16 + l15) * 72 + 32 + quad * 8];
#pragma unroll
    for (int mt = 0; mt < 5; ++mt) {
        acc[mt] = __builtin_amdgcn_mfma_f32_16x16x32_bf16(wa[mt][0], b0, acc[mt], 0, 0, 0);
        acc[mt] = __builtin_amdgcn_mfma_f32_16x16x32_bf16(wa[mt][1], b1, acc[mt], 0, 0, 0);
    }

    // ---- h rows (mt 1..4) direct: hb[b][hrow][n0 + w*16 + l15] ----
#pragma unroll
    for (int mt = 1; mt < 5; ++mt) {
#pragma unroll
        for (int r = 0; r < 4; ++r) {
            const int hrow = (mt - 1) * 16 + quad * 4 + r;
            hb[((size_t)(b * 64 + hrow)) * HW + n0 + w * 16 + l15] =
                __float2bfloat16(acc[0 + mt][r]);
        }
    }

    // ---- f/g rows (mt 0): transpose via LDS then coalesced float4 stores ----
#pragma unroll
    for (int r = 0; r < 4; r += 2) {
        __hip_bfloat16 t[2] = {__float2bfloat16(acc[0][r]),
                               __float2bfloat16(acc[0][r + 1])};
        *reinterpret_cast<unsigned*>(&fgT[(w * 16 + l15) * 24 + quad * 4 + r]) =
            *reinterpret_cast<const unsigned*>(t);
    }
    __syncthreads();
    if (tid < 64) {
        const size_t bn = (size_t)b * HW + n0 + tid;
        *(float4*)(fb + bn * 8) = *(const float4*)&fgT[tid * 24];
    } else if (tid < 128) {
        const int n = tid - 64;
        const size_t bn = (size_t)b * HW + n0 + n;
        *(float4*)(gb + bn * 8) = *(const float4*)&fgT[n * 24 + 8];
    }
}

// ---------------------------------------------------------------------------
// Kernel 2: zinv[b][n] = 1 / sum_i exp(f_i . g_n). Block owns 64 n and ALL i.
// All of f (64 KB) staged in LDS once; wave w covers i-strips w*16 + it*64.
// ---------------------------------------------------------------------------
__global__ __launch_bounds__(256) void k_z(
    const __hip_bfloat16* __restrict__ fb, const __hip_bfloat16* __restrict__ gb,
    float* __restrict__ zinv)
{
    __shared__ __align__(16) __hip_bfloat16 fS[4096 * 8];   // 64 KB
    __shared__ __align__(16) __hip_bfloat16 gS[64 * 8];
    __shared__ float zred[4][64];

    const int nt = blockIdx.x, b = blockIdx.y;
    const int n0 = nt * 64;
    const int tid = (int)threadIdx.x;
    const int w = tid >> 6, lane = tid & 63, quad = lane >> 4, l15 = lane & 15;

    const float4* fsrc = (const float4*)(fb + (size_t)b * HW * 8);
#pragma unroll
    for (int q = 0; q < 16; ++q)
        ((float4*)fS)[q * 256 + tid] = fsrc[q * 256 + tid];
    if (tid < 64)
        *(float4*)&gS[tid * 8] = *(const float4*)(gb + ((size_t)b * HW + n0 + tid) * 8);
    __syncthreads();

    const f32x4 cz = {0.f, 0.f, 0.f, 0.f};
    bf16x8 bgf[4];
#pragma unroll
    for (int ns = 0; ns < 4; ++ns) {
        bf16x8 v = {0, 0, 0, 0, 0, 0, 0, 0};
        if (quad == 0) v = *(const bf16x8*)&gS[(ns * 16 + l15) * 8];
        bgf[ns] = v;
    }

    float z[4] = {0.f, 0.f, 0.f, 0.f};
    for (int it = 0; it < 64; ++it) {
        const int i = it * 64 + w * 16;
        bf16x8 afr = {0, 0, 0, 0, 0, 0, 0, 0};
        if (quad == 0) afr = *(const bf16x8*)&fS[(i + l15) * 8];
#pragma unroll
        for (int ns = 0; ns < 4; ++ns) {
            f32x4 s = __builtin_amdgcn_mfma_f32_16x16x32_bf16(afr, bgf[ns], cz, 0, 0, 0);
            z[ns] += __expf(s[0]) + __expf(s[1]) + __expf(s[2]) + __expf(s[3]);
        }
    }

#pragma unroll
    for (int ns = 0; ns < 4; ++ns) {
        float v = z[ns];
        v += __shfl_xor(v, 16);
        v += __shfl_xor(v, 32);
        if (quad == 0) zred[w][ns * 16 + l15] = v;
    }
    __syncthreads();
    if (tid < 64) {
        float s = zred[0][tid] + zred[1][tid] + zred[2][tid] + zred[3][tid];
        zinv[(size_t)b * HW + n0 + tid] = 1.0f / s;
    }
}

// ---------------------------------------------------------------------------
// Kernel 3: attention. Per 64n-chunk: MFMA s-tile, p=exp(s)*zinv[n] (+tri
// mask), P->LDS bf16, MFMA P x H. Register-prefetch of next chunk's h/g/zinv
// overlaps VMEM with compute. NO atomics: each (hx,b,mt) block stores its
// own bf16 partial tile (coalesced), reduced in k_epi.
// ---------------------------------------------------------------------------
__global__ __launch_bounds__(256) void k_attn(
    const __hip_bfloat16* __restrict__ fb, const __hip_bfloat16* __restrict__ gb,
    const __hip_bfloat16* __restrict__ hb, const float* __restrict__ zinv,
    __hip_bfloat16* __restrict__ opart)
{
    __shared__ __align__(16) __hip_bfloat16 gS[64 * 8];
    __shared__ __align__(16) float zS[64];
    __shared__ __align__(16) __hip_bfloat16 hT[64 * 72];
    __shared__ __align__(16) __hip_bfloat16 pT[64 * 72];

    const int hx = blockIdx.x;               // 0..3 n-split
    const int b  = blockIdx.y;
    const int r  = blockIdx.z;
    const int mt = (r < 32) ? r : 95 - r;    // fold for load balance
    const int m0 = mt * 64;
    const int tid = (int)threadIdx.x;
    const int w = tid >> 6, lane = tid & 63, quad = lane >> 4, l15 = lane & 15;

    // hT staging coords for this thread (2 float4 = 32 B of the 8 KB tile)
    const int c0s = tid >> 3,          ch0 = tid & 7;
    const int c1s = (256 + tid) >> 3,  ch1 = (256 + tid) & 7;

    const f32x4 cz = {0.f, 0.f, 0.f, 0.f};

    bf16x8 af = {0, 0, 0, 0, 0, 0, 0, 0};
    if (quad == 0)
        af = *(const bf16x8*)(fb + ((size_t)b * HW + m0 + w * 16 + l15) * 8);

    f32x4 accO[4];
#pragma unroll
    for (int i = 0; i < 4; ++i) accO[i] = cz;

    const int nc0 = mt + hx;
    float4 hv0 = make_float4(0.f, 0.f, 0.f, 0.f);
    float4 hv1 = hv0, gv = hv0, zv = hv0;
    if (nc0 < 64) {   // prefetch first chunk
        const int n0 = nc0 * 64;
        hv0 = *(const float4*)(hb + ((size_t)(b * 64 + c0s)) * HW + n0 + ch0 * 8);
        hv1 = *(const float4*)(hb + ((size_t)(b * 64 + c1s)) * HW + n0 + ch1 * 8);
        if (tid < 64)      gv = *(const float4*)(gb + ((size_t)b * HW + n0 + tid) * 8);
        else if (tid < 80) zv = *(const float4*)(zinv + (size_t)b * HW + n0 + (tid - 64) * 4);
    }

    for (int nc = nc0; nc < 64; nc += 4) {
        __syncthreads();   // previous phase-B LDS reads complete
        *(float4*)&hT[c0s * 72 + ch0 * 8] = hv0;
        *(float4*)&hT[c1s * 72 + ch1 * 8] = hv1;
        if (tid < 64)      *(float4*)&gS[tid * 8] = gv;
        else if (tid < 80) *(float4*)&zS[(tid - 64) * 4] = zv;

        const int nn = nc + 4;
        if (nn < 64) {     // prefetch next chunk while computing this one
            const int n1 = nn * 64;
            hv0 = *(const float4*)(hb + ((size_t)(b * 64 + c0s)) * HW + n1 + ch0 * 8);
            hv1 = *(const float4*)(hb + ((size_t)(b * 64 + c1s)) * HW + n1 + ch1 * 8);
            if (tid < 64)      gv = *(const float4*)(gb + ((size_t)b * HW + n1 + tid) * 8);
            else if (tid < 80) zv = *(const float4*)(zinv + (size_t)b * HW + n1 + (tid - 64) * 4);
        }
        __syncthreads();

        const int n0 = nc * 64;
        const bool diag = (nc == mt);
        // ---- phase A: s = f.g^T; p = exp(s)*zinv; mask; -> pT (wave-private rows)
#pragma unroll
        for (int ns = 0; ns < 4; ++ns) {
            bf16x8 bg = {0, 0, 0, 0, 0, 0, 0, 0};
            if (quad == 0) bg = *(const bf16x8*)&gS[(ns * 16 + l15) * 8];
            f32x4 s = __builtin_amdgcn_mfma_f32_16x16x32_bf16(af, bg, cz, 0, 0, 0);
            const float zi = zS[ns * 16 + l15];
#pragma unroll
            for (int j = 0; j < 4; ++j) {
                float p = __expf(s[j]) * zi;
                if (diag) {
                    const int m = m0 + w * 16 + quad * 4 + j;
                    const int n = n0 + ns * 16 + l15;
                    if (n < m) p = 0.f;
                }
                pT[(w * 16 + quad * 4 + j) * 72 + ns * 16 + l15] = __float2bfloat16(p);
            }
        }
        // ---- phase B: accO += P x H ----
#pragma unroll
        for (int kb = 0; kb < 2; ++kb) {
            const bf16x8 ap =
                *(const bf16x8*)&pT[(w * 16 + l15) * 72 + kb * 32 + quad * 8];
#pragma unroll
            for (int cs = 0; cs < 4; ++cs) {
                const bf16x8 bh2 =
                    *(const bf16x8*)&hT[(cs * 16 + l15) * 72 + kb * 32 + quad * 8];
                accO[cs] = __builtin_amdgcn_mfma_f32_16x16x32_bf16(ap, bh2, accO[cs], 0, 0, 0);
            }
        }
    }

    // ---- epilogue: coalesced bf16 partial store, opart[hx][b][c][m] ----
#pragma unroll
    for (int cs = 0; cs < 4; ++cs) {
        const int c = cs * 16 + l15;
        __hip_bfloat16 tmp[4];
#pragma unroll
        for (int j = 0; j < 4; ++j) tmp[j] = __float2bfloat16(accO[cs][j]);
        *(float2*)(opart + ((size_t)((hx * NB + b) * 64 + c)) * HW + m0 + w * 16 + quad * 4) =
            *(const float2*)tmp;
    }
}

// ---------------------------------------------------------------------------
// Kernel 4: y = gamma * (sum of 4 partials) + x   (8 floats per thread)
// 1,048,576 output elements / 8 per thread = 131,072 threads = 512 blocks.
// ---------------------------------------------------------------------------
__global__ __launch_bounds__(256) void k_epi(
    const __hip_bfloat16* __restrict__ opart, const float* __restrict__ x,
    const float* __restrict__ gamma, float* __restrict__ y)
{
    const int t = blockIdx.x * 256 + (int)threadIdx.x;   // 131,072 threads
    const size_t e0 = (size_t)t * 8;
    const float ga = gamma[0];

    float acc[8] = {0, 0, 0, 0, 0, 0, 0, 0};
#pragma unroll
    for (int h = 0; h < 4; ++h) {
        const bf16x8 v = *(const bf16x8*)(opart + (size_t)h * (NB * CC * HW) + e0);
#pragma unroll
        for (int k = 0; k < 8; ++k) acc[k] += bf2f(v[k]);
    }
    const float4 x0 = *(const float4*)(x + e0);
    const float4 x1 = *(const float4*)(x + e0 + 4);
    float4 y0, y1;
    y0.x = ga * acc[0] + x0.x; y0.y = ga * acc[1] + x0.y;
    y0.z = ga * acc[2] + x0.z; y0.w = ga * acc[3] + x0.w;
    y1.x = ga * acc[4] + x1.x; y1.y = ga * acc[5] + x1.y;
    y1.z = ga * acc[6] + x1.z; y1.w = ga * acc[7] + x1.w;
    *(float4*)(y + e0) = y0;
    *(float4*)(y + e0 + 4) = y1;
}

extern "C" void kernel_launch(void* const* d_in, const int* in_sizes, int n_in,
                              void* d_out, int out_size, void* d_ws, size_t ws_size,
                              hipStream_t stream)
{
    const float* x     = (const float*)d_in[0];
    const float* Wf    = (const float*)d_in[1];
    const float* bf    = (const float*)d_in[2];
    const float* Wg    = (const float*)d_in[3];
    const float* bg    = (const float*)d_in[4];
    const float* Wh    = (const float*)d_in[5];
    const float* bh    = (const float*)d_in[6];
    const float* gamma = (const float*)d_in[7];

    char* ws = (char*)d_ws;
    __hip_bfloat16* fb = (__hip_bfloat16*)(ws + OFF_F);
    __hip_bfloat16* gb = (__hip_bfloat16*)(ws + OFF_G);
    __hip_bfloat16* hb = (__hip_bfloat16*)(ws + OFF_H);
    float* zinv = (float*)(ws + OFF_ZI);
    __hip_bfloat16* opart = (__hip_bfloat16*)(ws + OFF_O);
    float* y = (float*)d_out;

    k_prep<<<dim3(64, 4), 256, 0, stream>>>(x, Wf, bf, Wg, bg, Wh, bh, fb, gb, hb);
    k_z<<<dim3(64, 4), 256, 0, stream>>>(fb, gb, zinv);
    k_attn<<<dim3(4, 4, 64), 256, 0, stream>>>(fb, gb, hb, zinv, opart);
    k_epi<<<512, 256, 0, stream>>>(opart, x, gamma, y);
}